// Round 1
// baseline (3054.722 us; speedup 1.0000x reference)
//
#include <hip/hip_runtime.h>
#include <math.h>

#define S_DIM 1024
#define R_DIM 256
#define C_DIM 256
#define SCALE 0.17677669529663687f  // 1/sqrt(32)

__device__ __forceinline__ float wred(float v) {
#pragma unroll
  for (int m = 32; m >= 1; m >>= 1) v += __shfl_xor(v, m, 64);
  return v;
}

// ---------------- K1: LayerNorm + K/V projection + masked pool partials ----
// grid: (S/64, R), block 256. Block handles 64 s-values at one r.
__global__ __launch_bounds__(256, 2)
void k1_ln_kv(const float* __restrict__ mIn, const float* __restrict__ ln_g,
              const float* __restrict__ ln_b, const float* __restrict__ w_k,
              const float* __restrict__ w_v, const int* __restrict__ mask,
              float* __restrict__ mu_ws, float* __restrict__ rs_ws,
              float* __restrict__ K_ws, float* __restrict__ V_ws,
              float* __restrict__ pool_ws) {
  __shared__ float X[64 * 260];         // 64 rows x 256 (stride 260 pad)
  __shared__ float4 pool4[4][64];
  const int r  = blockIdx.y;
  const int s0 = blockIdx.x * 64;
  const int t  = threadIdx.x;
  const int lane = t & 63, wv = t >> 6;

  const float4 g4 = *(const float4*)(ln_g + lane * 4);
  const float4 b4 = *(const float4*)(ln_b + lane * 4);
  float4 pacc = make_float4(0.f, 0.f, 0.f, 0.f);

  for (int i = 0; i < 16; ++i) {
    const int sl = wv * 16 + i;
    const int s  = s0 + sl;
    const size_t base = ((size_t)s * R_DIM + r) * C_DIM;
    const float4 mv = *(const float4*)(mIn + base + lane * 4);
    const float mu = wred(mv.x + mv.y + mv.z + mv.w) * (1.f / 256.f);
    const float4 dv = make_float4(mv.x - mu, mv.y - mu, mv.z - mu, mv.w - mu);
    const float var =
        wred(dv.x * dv.x + dv.y * dv.y + dv.z * dv.z + dv.w * dv.w) * (1.f / 256.f);
    const float rs = rsqrtf(var + 1e-5f);
    const float4 xv = make_float4(dv.x * rs * g4.x + b4.x, dv.y * rs * g4.y + b4.y,
                                  dv.z * rs * g4.z + b4.z, dv.w * rs * g4.w + b4.w);
    *(float4*)(X + sl * 260 + lane * 4) = xv;
    if (lane == 0) {
      mu_ws[s * R_DIM + r] = mu;
      rs_ws[s * R_DIM + r] = rs;
    }
    if (mask[s * R_DIM + r]) {
      pacc.x += xv.x; pacc.y += xv.y; pacc.z += xv.z; pacc.w += xv.w;
    }
  }
  pool4[wv][lane] = pacc;
  __syncthreads();
  if (t < 64) {
    const float4 pa = pool4[0][t], pb = pool4[1][t], pc = pool4[2][t], pd = pool4[3][t];
    atomicAdd(&pool_ws[r * C_DIM + t * 4 + 0], pa.x + pb.x + pc.x + pd.x);
    atomicAdd(&pool_ws[r * C_DIM + t * 4 + 1], pa.y + pb.y + pc.y + pd.y);
    atomicAdd(&pool_ws[r * C_DIM + t * 4 + 2], pa.z + pb.z + pc.z + pd.z);
    atomicAdd(&pool_ws[r * C_DIM + t * 4 + 3], pa.w + pb.w + pc.w + pd.w);
  }
  // ---- phase B: [64 s][64 cols] GEMM, cols 0..31 = K, 32..63 = V ----
  const int tx = t & 15, ty = t >> 4;
  const float* W = (tx < 8) ? w_k : w_v;
  float* Out = (tx < 8) ? K_ws : V_ws;
  const int jj = (tx & 7) * 4;
  float4 acc[4];
#pragma unroll
  for (int i = 0; i < 4; ++i) acc[i] = make_float4(0.f, 0.f, 0.f, 0.f);
  for (int c = 0; c < 256; c += 4) {
    float4 xv4[4];
#pragma unroll
    for (int i = 0; i < 4; ++i) xv4[i] = *(const float4*)(X + (ty * 4 + i) * 260 + c);
#pragma unroll
    for (int u = 0; u < 4; ++u) {
      const float4 wv4 = *(const float4*)(W + (c + u) * 32 + jj);
#pragma unroll
      for (int i = 0; i < 4; ++i) {
        const float xs = reinterpret_cast<const float*>(&xv4[i])[u];
        acc[i].x += xs * wv4.x; acc[i].y += xs * wv4.y;
        acc[i].z += xs * wv4.z; acc[i].w += xs * wv4.w;
      }
    }
  }
#pragma unroll
  for (int i = 0; i < 4; ++i) {
    const int s = s0 + ty * 4 + i;
    *(float4*)(Out + ((size_t)s * R_DIM + r) * 32 + jj) = acc[i];
  }
}

// ---------------- K2: finalize pool, compute Q -----------------------------
// grid: R, block 256
__global__ __launch_bounds__(256, 2)
void k2_q(const float* __restrict__ pool_ws, const int* __restrict__ mask,
          const float* __restrict__ w_q, float* __restrict__ Q_ws) {
  __shared__ float qp[256];
  __shared__ float wsum[4];
  const int r = blockIdx.x, t = threadIdx.x;
  int cnt = 0;
  for (int s = t; s < S_DIM; s += 256) cnt += mask[s * R_DIM + r];
  float cf = wred((float)cnt);
  if ((t & 63) == 0) wsum[t >> 6] = cf;
  __syncthreads();
  const float denom = wsum[0] + wsum[1] + wsum[2] + wsum[3] + 1e-10f;
  qp[t] = pool_ws[r * C_DIM + t] / denom;
  __syncthreads();
  float acc = 0.f;
  for (int c = 0; c < 256; ++c) acc += qp[c] * w_q[c * 256 + t];
  Q_ws[r * 256 + t] = acc * SCALE;
}

// ---------------- K3: logits + softmax over s + O --------------------------
// grid: R, block 256
__global__ __launch_bounds__(256, 2)
void k3_attn(const float* __restrict__ K_ws, const float* __restrict__ V_ws,
             const int* __restrict__ mask, const float* __restrict__ Q_ws,
             float* __restrict__ O_ws) {
  __shared__ float q[256];
  __shared__ float lg[1024 * 9];
  __shared__ float kv[256 * 36];
  __shared__ float mh[8], inv[8];
  const int r = blockIdx.x, t = threadIdx.x;
  q[t] = Q_ws[r * 256 + t];

  for (int ch = 0; ch < 4; ++ch) {
    const int sb = ch * 256;
    __syncthreads();
    for (int f = t; f < 2048; f += 256) {
      const int sl = f >> 3, dq = f & 7;
      *(float4*)(kv + sl * 36 + dq * 4) =
          *(const float4*)(K_ws + ((size_t)(sb + sl) * R_DIM + r) * 32 + dq * 4);
    }
    __syncthreads();
    float kr[32];
#pragma unroll
    for (int dq = 0; dq < 8; ++dq)
      *(float4*)(kr + dq * 4) = *(float4*)(kv + t * 36 + dq * 4);
    const float bias = mask[(sb + t) * R_DIM + r] ? 0.f : -1e9f;
#pragma unroll
    for (int h = 0; h < 8; ++h) {
      float a = 0.f;
#pragma unroll
      for (int d = 0; d < 32; ++d) a += q[h * 32 + d] * kr[d];
      lg[(sb + t) * 9 + h] = a + bias;
    }
  }
  __syncthreads();
  {  // softmax stats: 32 threads per h
    const int h = t >> 5, l32 = t & 31;
    float mx = -INFINITY;
    for (int k = 0; k < 32; ++k) mx = fmaxf(mx, lg[(l32 + 32 * k) * 9 + h]);
#pragma unroll
    for (int mk = 16; mk >= 1; mk >>= 1) mx = fmaxf(mx, __shfl_xor(mx, mk, 64));
    float sm = 0.f;
    for (int k = 0; k < 32; ++k) sm += expf(lg[(l32 + 32 * k) * 9 + h] - mx);
#pragma unroll
    for (int mk = 16; mk >= 1; mk >>= 1) sm += __shfl_xor(sm, mk, 64);
    if (l32 == 0) { mh[h] = mx; inv[h] = 1.f / sm; }
  }
  __syncthreads();
  for (int f = t; f < 8192; f += 256) {  // A in place
    const int s = f >> 3, h = f & 7;
    lg[s * 9 + h] = expf(lg[s * 9 + h] - mh[h]) * inv[h];
  }
  const int h = t >> 5, d = t & 31;
  float o = 0.f;
  for (int ch = 0; ch < 4; ++ch) {
    const int sb = ch * 256;
    __syncthreads();
    for (int f = t; f < 2048; f += 256) {
      const int sl = f >> 3, dq = f & 7;
      *(float4*)(kv + sl * 36 + dq * 4) =
          *(const float4*)(V_ws + ((size_t)(sb + sl) * R_DIM + r) * 32 + dq * 4);
    }
    __syncthreads();
    for (int sl = 0; sl < 256; ++sl)
      o += lg[(sb + sl) * 9 + h] * kv[sl * 36 + d];
  }
  O_ws[r * 256 + t] = o;
}

// ---------------- K4: x -> sigmoid(x wg + bg)*O -> wo + bo -----------------
// grid: (S*R)/64, block 256. 64 consecutive positions (same s, 64 r's).
__global__ __launch_bounds__(256, 2)
void k4_out(const float* __restrict__ mIn, const float* __restrict__ ln_g,
            const float* __restrict__ ln_b, const float* __restrict__ mu_ws,
            const float* __restrict__ rs_ws, const float* __restrict__ w_g,
            const float* __restrict__ b_g, const float* __restrict__ O_ws,
            const float* __restrict__ w_o, const float* __restrict__ b_o,
            float* __restrict__ out) {
  __shared__ float X[64 * 260];
  const int t = threadIdx.x;
  const int p0 = blockIdx.x * 64;
  const int lane = t & 63, wv = t >> 6;
  {  // phase A: recompute x from stored mu/rsig
    const float4 g4 = *(const float4*)(ln_g + lane * 4);
    const float4 b4 = *(const float4*)(ln_b + lane * 4);
    for (int i = 0; i < 16; ++i) {
      const int pl = wv * 16 + i;
      const size_t p = (size_t)(p0 + pl);
      const float mu = mu_ws[p], rs = rs_ws[p];
      const float4 mv = *(const float4*)(mIn + p * 256 + lane * 4);
      const float4 xv =
          make_float4((mv.x - mu) * rs * g4.x + b4.x, (mv.y - mu) * rs * g4.y + b4.y,
                      (mv.z - mu) * rs * g4.z + b4.z, (mv.w - mu) * rs * g4.w + b4.w);
      *(float4*)(X + pl * 260 + lane * 4) = xv;
    }
  }
  __syncthreads();
  const int tx = t & 15, ty = t >> 4;
  const int j0 = tx * 16;
  const int r0 = p0 & 255;
  float4 acc[4][4];
  {  // phase B: gl = X @ w_g + b_g
#pragma unroll
    for (int q = 0; q < 4; ++q) {
      const float4 bg4 = *(const float4*)(b_g + j0 + q * 4);
#pragma unroll
      for (int i = 0; i < 4; ++i) acc[i][q] = bg4;
    }
    for (int c = 0; c < 256; c += 4) {
      float4 xv4[4];
#pragma unroll
      for (int i = 0; i < 4; ++i) xv4[i] = *(const float4*)(X + (ty * 4 + i) * 260 + c);
#pragma unroll
      for (int u = 0; u < 4; ++u) {
        float4 wv4[4];
#pragma unroll
        for (int q = 0; q < 4; ++q)
          wv4[q] = *(const float4*)(w_g + (size_t)(c + u) * 256 + j0 + q * 4);
#pragma unroll
        for (int i = 0; i < 4; ++i) {
          const float xs = reinterpret_cast<const float*>(&xv4[i])[u];
#pragma unroll
          for (int q = 0; q < 4; ++q) {
            acc[i][q].x += xs * wv4[q].x; acc[i][q].y += xs * wv4[q].y;
            acc[i][q].z += xs * wv4[q].z; acc[i][q].w += xs * wv4[q].w;
          }
        }
      }
    }
  }
  __syncthreads();  // everyone done reading X
  // T = sigmoid(gl) * O[r]  (overwrite X)
#pragma unroll
  for (int i = 0; i < 4; ++i) {
    const int r = r0 + ty * 4 + i;
#pragma unroll
    for (int q = 0; q < 4; ++q) {
      const float4 o4 = *(const float4*)(O_ws + r * 256 + j0 + q * 4);
      const float4 a = acc[i][q];
      float4 tv;
      tv.x = o4.x / (1.f + expf(-a.x));
      tv.y = o4.y / (1.f + expf(-a.y));
      tv.z = o4.z / (1.f + expf(-a.z));
      tv.w = o4.w / (1.f + expf(-a.w));
      *(float4*)(X + (ty * 4 + i) * 260 + j0 + q * 4) = tv;
    }
  }
  __syncthreads();
  {  // phase C: out = T @ w_o + b_o
#pragma unroll
    for (int q = 0; q < 4; ++q) {
      const float4 bo4 = *(const float4*)(b_o + j0 + q * 4);
#pragma unroll
      for (int i = 0; i < 4; ++i) acc[i][q] = bo4;
    }
    for (int c = 0; c < 256; c += 4) {
      float4 xv4[4];
#pragma unroll
      for (int i = 0; i < 4; ++i) xv4[i] = *(const float4*)(X + (ty * 4 + i) * 260 + c);
#pragma unroll
      for (int u = 0; u < 4; ++u) {
        float4 wv4[4];
#pragma unroll
        for (int q = 0; q < 4; ++q)
          wv4[q] = *(const float4*)(w_o + (size_t)(c + u) * 256 + j0 + q * 4);
#pragma unroll
        for (int i = 0; i < 4; ++i) {
          const float xs = reinterpret_cast<const float*>(&xv4[i])[u];
#pragma unroll
          for (int q = 0; q < 4; ++q) {
            acc[i][q].x += xs * wv4[q].x; acc[i][q].y += xs * wv4[q].y;
            acc[i][q].z += xs * wv4[q].z; acc[i][q].w += xs * wv4[q].w;
          }
        }
      }
    }
#pragma unroll
    for (int i = 0; i < 4; ++i) {
      const size_t p = (size_t)(p0 + ty * 4 + i);
#pragma unroll
      for (int q = 0; q < 4; ++q)
        *(float4*)(out + p * 256 + j0 + q * 4) = acc[i][q];
    }
  }
}

extern "C" void kernel_launch(void* const* d_in, const int* in_sizes, int n_in,
                              void* d_out, int out_size, void* d_ws, size_t ws_size,
                              hipStream_t stream) {
  const float* mIn  = (const float*)d_in[0];
  const float* ln_g = (const float*)d_in[1];
  const float* ln_b = (const float*)d_in[2];
  const float* w_q  = (const float*)d_in[3];
  const float* w_k  = (const float*)d_in[4];
  const float* w_v  = (const float*)d_in[5];
  const float* w_g  = (const float*)d_in[6];
  const float* b_g  = (const float*)d_in[7];
  const float* w_o  = (const float*)d_in[8];
  const float* b_o  = (const float*)d_in[9];
  const int*   mask = (const int*)d_in[10];
  float* outp = (float*)d_out;

  char* ws = (char*)d_ws;
  const size_t NP = (size_t)S_DIM * R_DIM;      // 262144 positions
  float* mu_ws   = (float*)ws;                  // NP
  float* rs_ws   = mu_ws + NP;                  // NP
  float* K_ws    = rs_ws + NP;                  // NP*32
  float* V_ws    = K_ws + NP * 32;              // NP*32
  float* pool_ws = V_ws + NP * 32;              // 256*256
  float* Q_ws    = pool_ws + 65536;             // 256*256
  float* O_ws    = Q_ws + 65536;                // 256*256

  hipMemsetAsync(pool_ws, 0, 65536 * sizeof(float), stream);

  k1_ln_kv<<<dim3(S_DIM / 64, R_DIM), 256, 0, stream>>>(
      mIn, ln_g, ln_b, w_k, w_v, mask, mu_ws, rs_ws, K_ws, V_ws, pool_ws);
  k2_q<<<R_DIM, 256, 0, stream>>>(pool_ws, mask, w_q, Q_ws);
  k3_attn<<<R_DIM, 256, 0, stream>>>(K_ws, V_ws, mask, Q_ws, O_ws);
  k4_out<<<(S_DIM * R_DIM) / 64, 256, 0, stream>>>(
      mIn, ln_g, ln_b, mu_ws, rs_ws, w_g, b_g, O_ws, w_o, b_o, outp);
}

// Round 2
// 527.994 us; speedup vs baseline: 5.7855x; 5.7855x over previous
//
#include <hip/hip_runtime.h>
#include <math.h>

#define S_DIM 1024
#define R_DIM 256
#define C_DIM 256
#define SCALE 0.17677669529663687f  // 1/sqrt(32)

typedef short bf16x8 __attribute__((ext_vector_type(8)));
typedef float f32x4 __attribute__((ext_vector_type(4)));

__device__ __forceinline__ float wred(float v) {
#pragma unroll
  for (int m = 32; m >= 1; m >>= 1) v += __shfl_xor(v, m, 64);
  return v;
}

__device__ __forceinline__ short f2bf(float f) {
  union { float f; unsigned u; } v;
  v.f = f;
  unsigned r = v.u + 0x7fffu + ((v.u >> 16) & 1u);  // RNE
  return (short)(r >> 16);
}

// ---------------- K0: pre-swizzle w_g / w_o into B-fragment bf16 layout ----
// slot (kb, n, g) holds bf16 W[kb*32+g*8+j][n], j=0..7. 8192 slots per weight.
__global__ __launch_bounds__(256)
void k0_prep(const float* __restrict__ w_g, const float* __restrict__ w_o,
             short* __restrict__ wgB, short* __restrict__ woB) {
  const int id = blockIdx.x * 256 + threadIdx.x;  // 16384 ids
  const int which = id >> 13;
  const int s = id & 8191;
  const int n = s & 255, g = (s >> 8) & 3, kb = s >> 10;
  const float* W = which ? w_o : w_g;
  short* Out = which ? woB : wgB;
#pragma unroll
  for (int j = 0; j < 8; ++j)
    Out[(((size_t)kb * 256 + n) * 4 + g) * 8 + j] =
        f2bf(W[(size_t)(kb * 32 + g * 8 + j) * 256 + n]);
}

// ---------------- K1: LayerNorm + K/V projection + masked pool partials ----
__global__ __launch_bounds__(256, 2)
void k1_ln_kv(const float* __restrict__ mIn, const float* __restrict__ ln_g,
              const float* __restrict__ ln_b, const float* __restrict__ w_k,
              const float* __restrict__ w_v, const int* __restrict__ mask,
              float* __restrict__ mu_ws, float* __restrict__ rs_ws,
              float* __restrict__ K_ws, float* __restrict__ V_ws,
              float* __restrict__ pool_ws) {
  __shared__ float X[64 * 260];
  __shared__ float4 pool4[4][64];
  const int r  = blockIdx.y;
  const int s0 = blockIdx.x * 64;
  const int t  = threadIdx.x;
  const int lane = t & 63, wv = t >> 6;

  const float4 g4 = *(const float4*)(ln_g + lane * 4);
  const float4 b4 = *(const float4*)(ln_b + lane * 4);
  float4 pacc = make_float4(0.f, 0.f, 0.f, 0.f);

  for (int i = 0; i < 16; ++i) {
    const int sl = wv * 16 + i;
    const int s  = s0 + sl;
    const size_t base = ((size_t)s * R_DIM + r) * C_DIM;
    const float4 mv = *(const float4*)(mIn + base + lane * 4);
    const float mu = wred(mv.x + mv.y + mv.z + mv.w) * (1.f / 256.f);
    const float4 dv = make_float4(mv.x - mu, mv.y - mu, mv.z - mu, mv.w - mu);
    const float var =
        wred(dv.x * dv.x + dv.y * dv.y + dv.z * dv.z + dv.w * dv.w) * (1.f / 256.f);
    const float rs = rsqrtf(var + 1e-5f);
    const float4 xv = make_float4(dv.x * rs * g4.x + b4.x, dv.y * rs * g4.y + b4.y,
                                  dv.z * rs * g4.z + b4.z, dv.w * rs * g4.w + b4.w);
    *(float4*)(X + sl * 260 + lane * 4) = xv;
    if (lane == 0) {
      mu_ws[s * R_DIM + r] = mu;
      rs_ws[s * R_DIM + r] = rs;
    }
    if (mask[s * R_DIM + r]) {
      pacc.x += xv.x; pacc.y += xv.y; pacc.z += xv.z; pacc.w += xv.w;
    }
  }
  pool4[wv][lane] = pacc;
  __syncthreads();
  if (t < 64) {
    const float4 pa = pool4[0][t], pb = pool4[1][t], pc = pool4[2][t], pd = pool4[3][t];
    atomicAdd(&pool_ws[r * C_DIM + t * 4 + 0], pa.x + pb.x + pc.x + pd.x);
    atomicAdd(&pool_ws[r * C_DIM + t * 4 + 1], pa.y + pb.y + pc.y + pd.y);
    atomicAdd(&pool_ws[r * C_DIM + t * 4 + 2], pa.z + pb.z + pc.z + pd.z);
    atomicAdd(&pool_ws[r * C_DIM + t * 4 + 3], pa.w + pb.w + pc.w + pd.w);
  }
  const int tx = t & 15, ty = t >> 4;
  const float* W = (tx < 8) ? w_k : w_v;
  float* Out = (tx < 8) ? K_ws : V_ws;
  const int jj = (tx & 7) * 4;
  float4 acc[4];
#pragma unroll
  for (int i = 0; i < 4; ++i) acc[i] = make_float4(0.f, 0.f, 0.f, 0.f);
  for (int c = 0; c < 256; c += 4) {
    float4 xv4[4];
#pragma unroll
    for (int i = 0; i < 4; ++i) xv4[i] = *(const float4*)(X + (ty * 4 + i) * 260 + c);
#pragma unroll
    for (int u = 0; u < 4; ++u) {
      const float4 wv4 = *(const float4*)(W + (c + u) * 32 + jj);
#pragma unroll
      for (int i = 0; i < 4; ++i) {
        const float xs = reinterpret_cast<const float*>(&xv4[i])[u];
        acc[i].x += xs * wv4.x; acc[i].y += xs * wv4.y;
        acc[i].z += xs * wv4.z; acc[i].w += xs * wv4.w;
      }
    }
  }
#pragma unroll
  for (int i = 0; i < 4; ++i) {
    const int s = s0 + ty * 4 + i;
    *(float4*)(Out + ((size_t)s * R_DIM + r) * 32 + jj) = acc[i];
  }
}

// ---------------- K2: finalize pool, compute Q -----------------------------
__global__ __launch_bounds__(256, 2)
void k2_q(const float* __restrict__ pool_ws, const int* __restrict__ mask,
          const float* __restrict__ w_q, float* __restrict__ Q_ws) {
  __shared__ float qp[256];
  __shared__ float wsum[4];
  const int r = blockIdx.x, t = threadIdx.x;
  int cnt = 0;
  for (int s = t; s < S_DIM; s += 256) cnt += mask[s * R_DIM + r];
  float cf = wred((float)cnt);
  if ((t & 63) == 0) wsum[t >> 6] = cf;
  __syncthreads();
  const float denom = wsum[0] + wsum[1] + wsum[2] + wsum[3] + 1e-10f;
  qp[t] = pool_ws[r * C_DIM + t] / denom;
  __syncthreads();
  float acc = 0.f;
  for (int c = 0; c < 256; ++c) acc += qp[c] * w_q[c * 256 + t];
  Q_ws[r * 256 + t] = acc * SCALE;
}

// ---------------- K3: logits + softmax over s + O --------------------------
__global__ __launch_bounds__(256, 2)
void k3_attn(const float* __restrict__ K_ws, const float* __restrict__ V_ws,
             const int* __restrict__ mask, const float* __restrict__ Q_ws,
             float* __restrict__ O_ws) {
  __shared__ float q[256];
  __shared__ float lg[1024 * 9];
  __shared__ float kv[256 * 36];
  __shared__ float mh[8], inv[8];
  const int r = blockIdx.x, t = threadIdx.x;
  q[t] = Q_ws[r * 256 + t];

  for (int ch = 0; ch < 4; ++ch) {
    const int sb = ch * 256;
    __syncthreads();
    for (int f = t; f < 2048; f += 256) {
      const int sl = f >> 3, dq = f & 7;
      *(float4*)(kv + sl * 36 + dq * 4) =
          *(const float4*)(K_ws + ((size_t)(sb + sl) * R_DIM + r) * 32 + dq * 4);
    }
    __syncthreads();
    float kr[32];
#pragma unroll
    for (int dq = 0; dq < 8; ++dq)
      *(float4*)(kr + dq * 4) = *(float4*)(kv + t * 36 + dq * 4);
    const float bias = mask[(sb + t) * R_DIM + r] ? 0.f : -1e9f;
#pragma unroll
    for (int h = 0; h < 8; ++h) {
      float a = 0.f;
#pragma unroll
      for (int d = 0; d < 32; ++d) a += q[h * 32 + d] * kr[d];
      lg[(sb + t) * 9 + h] = a + bias;
    }
  }
  __syncthreads();
  {
    const int h = t >> 5, l32 = t & 31;
    float mx = -INFINITY;
    for (int k = 0; k < 32; ++k) mx = fmaxf(mx, lg[(l32 + 32 * k) * 9 + h]);
#pragma unroll
    for (int mk = 16; mk >= 1; mk >>= 1) mx = fmaxf(mx, __shfl_xor(mx, mk, 64));
    float sm = 0.f;
    for (int k = 0; k < 32; ++k) sm += expf(lg[(l32 + 32 * k) * 9 + h] - mx);
#pragma unroll
    for (int mk = 16; mk >= 1; mk >>= 1) sm += __shfl_xor(sm, mk, 64);
    if (l32 == 0) { mh[h] = mx; inv[h] = 1.f / sm; }
  }
  __syncthreads();
  for (int f = t; f < 8192; f += 256) {
    const int s = f >> 3, h = f & 7;
    lg[s * 9 + h] = expf(lg[s * 9 + h] - mh[h]) * inv[h];
  }
  const int h = t >> 5, d = t & 31;
  float o = 0.f;
  for (int ch = 0; ch < 4; ++ch) {
    const int sb = ch * 256;
    __syncthreads();
    for (int f = t; f < 2048; f += 256) {
      const int sl = f >> 3, dq = f & 7;
      *(float4*)(kv + sl * 36 + dq * 4) =
          *(const float4*)(V_ws + ((size_t)(sb + sl) * R_DIM + r) * 32 + dq * 4);
    }
    __syncthreads();
    for (int sl = 0; sl < 256; ++sl)
      o += lg[(sb + sl) * 9 + h] * kv[sl * 36 + d];
  }
  O_ws[r * 256 + t] = o;
}

// ---------------- K4: MFMA gate GEMM + sigmoid*O + output GEMM -------------
// grid: 4096 blocks, 256 threads (4 waves). Block = 64 positions x 256 outs.
// A_lds slot ((mi*8+kb)*64 + l) holds bf16x8 A[mi*16 + (l&15)][kb*32+(l>>4)*8+j].
__global__ __launch_bounds__(256, 2)
void k4_mfma(const float* __restrict__ mIn, const float* __restrict__ ln_g,
             const float* __restrict__ ln_b, const float* __restrict__ mu_ws,
             const float* __restrict__ rs_ws, const short* __restrict__ wgB,
             const float* __restrict__ b_g, const float* __restrict__ O_ws,
             const short* __restrict__ woB, const float* __restrict__ b_o,
             float* __restrict__ out) {
  __shared__ __align__(16) short A_lds[2048 * 8];  // 32 KB
  const int t = threadIdx.x;
  const int p0 = blockIdx.x * 64;
  const int r0 = p0 & 255;
  const int l = t & 63;
  const int w = t >> 6;
  const int lm = l & 15;
  const int g = l >> 4;

  // ---- phase A: recompute X (bf16) into fragment-ordered LDS ----
  {
    const int row = w * 16 + lm;
    const size_t p = (size_t)(p0 + row);
    const float mu = mu_ws[p], rs = rs_ws[p];
    const float* mrow = mIn + p * 256 + g * 8;
    const float* gp = ln_g + g * 8;
    const float* bp = ln_b + g * 8;
#pragma unroll
    for (int kb = 0; kb < 8; ++kb) {
      const float4 m0 = *(const float4*)(mrow + kb * 32);
      const float4 m1 = *(const float4*)(mrow + kb * 32 + 4);
      const float4 g0 = *(const float4*)(gp + kb * 32);
      const float4 g1 = *(const float4*)(gp + kb * 32 + 4);
      const float4 b0 = *(const float4*)(bp + kb * 32);
      const float4 b1 = *(const float4*)(bp + kb * 32 + 4);
      bf16x8 xf;
      xf[0] = f2bf((m0.x - mu) * rs * g0.x + b0.x);
      xf[1] = f2bf((m0.y - mu) * rs * g0.y + b0.y);
      xf[2] = f2bf((m0.z - mu) * rs * g0.z + b0.z);
      xf[3] = f2bf((m0.w - mu) * rs * g0.w + b0.w);
      xf[4] = f2bf((m1.x - mu) * rs * g1.x + b1.x);
      xf[5] = f2bf((m1.y - mu) * rs * g1.y + b1.y);
      xf[6] = f2bf((m1.z - mu) * rs * g1.z + b1.z);
      xf[7] = f2bf((m1.w - mu) * rs * g1.w + b1.w);
      *(bf16x8*)(A_lds + ((w * 8 + kb) * 64 + l) * 8) = xf;
    }
  }
  __syncthreads();

  const int nB = w * 64;
  const int col = nB + lm;
  f32x4 acc[4][4];

  // ---- gate GEMM: gl = X @ w_g + b_g ----
#pragma unroll
  for (int ni = 0; ni < 4; ++ni) {
    const float bg = b_g[col + ni * 16];
#pragma unroll
    for (int mi = 0; mi < 4; ++mi) acc[mi][ni] = (f32x4){bg, bg, bg, bg};
  }
#pragma unroll
  for (int kb = 0; kb < 8; ++kb) {
    bf16x8 a[4], bb[4];
#pragma unroll
    for (int mi = 0; mi < 4; ++mi)
      a[mi] = *(const bf16x8*)(A_lds + ((mi * 8 + kb) * 64 + l) * 8);
#pragma unroll
    for (int ni = 0; ni < 4; ++ni)
      bb[ni] = *(const bf16x8*)(wgB + (((size_t)kb * 256 + col + ni * 16) * 4 + g) * 8);
#pragma unroll
    for (int mi = 0; mi < 4; ++mi)
#pragma unroll
      for (int ni = 0; ni < 4; ++ni)
        acc[mi][ni] = __builtin_amdgcn_mfma_f32_16x16x32_bf16(a[mi], bb[ni], acc[mi][ni], 0, 0, 0);
  }
  __syncthreads();

  // ---- T = sigmoid(gl) * O, scattered back to LDS in A-frag layout ----
#pragma unroll
  for (int mi = 0; mi < 4; ++mi) {
#pragma unroll
    for (int ni = 0; ni < 4; ++ni) {
      const int c2 = col + ni * 16;
      const int kb2 = c2 >> 5, g2 = (c2 >> 3) & 3, b2 = c2 & 7;
#pragma unroll
      for (int reg = 0; reg < 4; ++reg) {
        const int row = mi * 16 + g * 4 + reg;
        const float o = O_ws[(r0 + row) * 256 + c2];
        const float gl = acc[mi][ni][reg];
        const float tv = o / (1.f + expf(-gl));
        A_lds[((mi * 8 + kb2) * 64 + (g * 4 + reg) + g2 * 16) * 8 + b2] = f2bf(tv);
      }
    }
  }
  __syncthreads();

  // ---- output GEMM: out = T @ w_o + b_o ----
#pragma unroll
  for (int ni = 0; ni < 4; ++ni) {
    const float bo = b_o[col + ni * 16];
#pragma unroll
    for (int mi = 0; mi < 4; ++mi) acc[mi][ni] = (f32x4){bo, bo, bo, bo};
  }
#pragma unroll
  for (int kb = 0; kb < 8; ++kb) {
    bf16x8 a[4], bb[4];
#pragma unroll
    for (int mi = 0; mi < 4; ++mi)
      a[mi] = *(const bf16x8*)(A_lds + ((mi * 8 + kb) * 64 + l) * 8);
#pragma unroll
    for (int ni = 0; ni < 4; ++ni)
      bb[ni] = *(const bf16x8*)(woB + (((size_t)kb * 256 + col + ni * 16) * 4 + g) * 8);
#pragma unroll
    for (int mi = 0; mi < 4; ++mi)
#pragma unroll
      for (int ni = 0; ni < 4; ++ni)
        acc[mi][ni] = __builtin_amdgcn_mfma_f32_16x16x32_bf16(a[mi], bb[ni], acc[mi][ni], 0, 0, 0);
  }

  // ---- store ----
#pragma unroll
  for (int mi = 0; mi < 4; ++mi)
#pragma unroll
    for (int ni = 0; ni < 4; ++ni)
#pragma unroll
      for (int reg = 0; reg < 4; ++reg) {
        const int row = mi * 16 + g * 4 + reg;
        out[(size_t)(p0 + row) * 256 + col + ni * 16] = acc[mi][ni][reg];
      }
}

extern "C" void kernel_launch(void* const* d_in, const int* in_sizes, int n_in,
                              void* d_out, int out_size, void* d_ws, size_t ws_size,
                              hipStream_t stream) {
  const float* mIn  = (const float*)d_in[0];
  const float* ln_g = (const float*)d_in[1];
  const float* ln_b = (const float*)d_in[2];
  const float* w_q  = (const float*)d_in[3];
  const float* w_k  = (const float*)d_in[4];
  const float* w_v  = (const float*)d_in[5];
  const float* w_g  = (const float*)d_in[6];
  const float* b_g  = (const float*)d_in[7];
  const float* w_o  = (const float*)d_in[8];
  const float* b_o  = (const float*)d_in[9];
  const int*   mask = (const int*)d_in[10];
  float* outp = (float*)d_out;

  char* ws = (char*)d_ws;
  const size_t NP = (size_t)S_DIM * R_DIM;
  float* mu_ws   = (float*)ws;
  float* rs_ws   = mu_ws + NP;
  float* K_ws    = rs_ws + NP;
  float* V_ws    = K_ws + NP * 32;
  float* pool_ws = V_ws + NP * 32;
  float* Q_ws    = pool_ws + 65536;
  float* O_ws    = Q_ws + 65536;
  short* wgB     = (short*)(O_ws + 65536);
  short* woB     = wgB + 65536;

  hipMemsetAsync(pool_ws, 0, 65536 * sizeof(float), stream);

  k0_prep<<<64, 256, 0, stream>>>(w_g, w_o, wgB, woB);
  k1_ln_kv<<<dim3(S_DIM / 64, R_DIM), 256, 0, stream>>>(
      mIn, ln_g, ln_b, w_k, w_v, mask, mu_ws, rs_ws, K_ws, V_ws, pool_ws);
  k2_q<<<R_DIM, 256, 0, stream>>>(pool_ws, mask, w_q, Q_ws);
  k3_attn<<<R_DIM, 256, 0, stream>>>(K_ws, V_ws, mask, Q_ws, O_ws);
  k4_mfma<<<S_DIM * R_DIM / 64, 256, 0, stream>>>(
      mIn, ln_g, ln_b, mu_ws, rs_ws, wgB, b_g, O_ws, woB, b_o, outp);
}

// Round 3
// 376.617 us; speedup vs baseline: 8.1109x; 1.4019x over previous
//
#include <hip/hip_runtime.h>
#include <math.h>

#define S_DIM 1024
#define R_DIM 256
#define C_DIM 256
#define SCALE 0.17677669529663687f  // 1/sqrt(32)

typedef short bf16x8 __attribute__((ext_vector_type(8)));
typedef float f32x4 __attribute__((ext_vector_type(4)));

__device__ __forceinline__ float wred(float v) {
#pragma unroll
  for (int m = 32; m >= 1; m >>= 1) v += __shfl_xor(v, m, 64);
  return v;
}

__device__ __forceinline__ short f2bf(float f) {
  union { float f; unsigned u; } v;
  v.f = f;
  unsigned r = v.u + 0x7fffu + ((v.u >> 16) & 1u);  // RNE
  return (short)(r >> 16);
}

__device__ __forceinline__ float bf2f(short s) {
  union { unsigned u; float f; } v;
  v.u = ((unsigned)(unsigned short)s) << 16;
  return v.f;
}

// ---------------- K0: pre-swizzle weights into B-fragment bf16 layouts ----
// wgB/woB: slot (kb, n(256), g) -> W[kb*32+g*8+j][n].  8192 slots each.
// wkvB:    slot (kb, n(64), g)  -> n<32: w_k[.][n], n>=32: w_v[.][n-32]. 2048 slots.
__global__ __launch_bounds__(256)
void k0_prep(const float* __restrict__ w_g, const float* __restrict__ w_o,
             const float* __restrict__ w_k, const float* __restrict__ w_v,
             short* __restrict__ wgB, short* __restrict__ woB,
             short* __restrict__ wkvB) {
  const int id = blockIdx.x * 256 + threadIdx.x;  // 18432 ids
  if (id < 16384) {
    const int which = id >> 13;
    const int s = id & 8191;
    const int n = s & 255, g = (s >> 8) & 3, kb = s >> 10;
    const float* W = which ? w_o : w_g;
    short* Out = which ? woB : wgB;
#pragma unroll
    for (int j = 0; j < 8; ++j)
      Out[(((size_t)kb * 256 + n) * 4 + g) * 8 + j] =
          f2bf(W[(size_t)(kb * 32 + g * 8 + j) * 256 + n]);
  } else {
    const int s = id - 16384;  // 0..2047
    const int n = s & 63, g = (s >> 6) & 3, kb = s >> 8;
    const float* W = (n < 32) ? w_k : w_v;
    const int nn = n & 31;
#pragma unroll
    for (int j = 0; j < 8; ++j)
      wkvB[(((size_t)kb * 64 + n) * 4 + g) * 8 + j] =
          f2bf(W[(size_t)(kb * 32 + g * 8 + j) * 32 + nn]);
  }
}

// ---------------- K1: LN -> bf16 frag LDS -> MFMA K/V + pool --------------
// grid: (16, 256) = 4096 blocks of 256 threads. Block: 64 s-rows at one r.
__global__ __launch_bounds__(256, 3)
void k1_ln_kv(const float* __restrict__ mIn, const float* __restrict__ ln_g,
              const float* __restrict__ ln_b, const short* __restrict__ wkvB,
              const int* __restrict__ mask,
              float* __restrict__ mu_ws, float* __restrict__ rs_ws,
              float* __restrict__ K_ws, float* __restrict__ V_ws,
              float* __restrict__ pool_ws) {
  __shared__ __align__(16) short A_lds[2048 * 8];  // 32 KB, frag-ordered X
  __shared__ float mask_s[64];
  __shared__ float4 poolp[4][64];                  // 4 KB
  const int r  = blockIdx.y;
  const int s0 = blockIdx.x * 64;
  const int t  = threadIdx.x;

  if (t < 64) mask_s[t] = mask[(s0 + t) * R_DIM + r] ? 1.f : 0.f;

  // ---- pass 1: LN stats (4-lane reduce) + bf16 frag write ----
  {
    const int rw = t >> 2;  // row 0..63
    const int q  = t & 3;   // col quarter (cols q*64..q*64+63)
    const size_t p = (size_t)(s0 + rw) * R_DIM + r;
    const float* src = mIn + p * C_DIM + q * 64;
    float4 xv[16];
    float sum = 0.f, ssq = 0.f;
#pragma unroll
    for (int i = 0; i < 16; ++i) {
      xv[i] = *(const float4*)(src + i * 4);
      sum += xv[i].x + xv[i].y + xv[i].z + xv[i].w;
      ssq += xv[i].x * xv[i].x + xv[i].y * xv[i].y + xv[i].z * xv[i].z +
             xv[i].w * xv[i].w;
    }
    sum += __shfl_xor(sum, 1, 64); ssq += __shfl_xor(ssq, 1, 64);
    sum += __shfl_xor(sum, 2, 64); ssq += __shfl_xor(ssq, 2, 64);
    const float mu = sum * (1.f / 256.f);
    const float var = ssq * (1.f / 256.f) - mu * mu;
    const float rs = rsqrtf(var + 1e-5f);
    if (q == 0) { mu_ws[p] = mu; rs_ws[p] = rs; }

    const int gw = rw >> 4;    // owning wave-group in MFMA phase
    const int lf0 = rw & 15;
#pragma unroll
    for (int kh = 0; kh < 2; ++kh) {
      const int kb = 2 * q + kh;
#pragma unroll
      for (int g = 0; g < 4; ++g) {
        const int lidx = kh * 32 + g * 8;  // local col offset 0..56
        const float4 a0 = xv[lidx >> 2], a1 = xv[(lidx >> 2) + 1];
        const float4 g0 = *(const float4*)(ln_g + kb * 32 + g * 8);
        const float4 g1 = *(const float4*)(ln_g + kb * 32 + g * 8 + 4);
        const float4 b0 = *(const float4*)(ln_b + kb * 32 + g * 8);
        const float4 b1 = *(const float4*)(ln_b + kb * 32 + g * 8 + 4);
        bf16x8 f;
        f[0] = f2bf((a0.x - mu) * rs * g0.x + b0.x);
        f[1] = f2bf((a0.y - mu) * rs * g0.y + b0.y);
        f[2] = f2bf((a0.z - mu) * rs * g0.z + b0.z);
        f[3] = f2bf((a0.w - mu) * rs * g0.w + b0.w);
        f[4] = f2bf((a1.x - mu) * rs * g1.x + b1.x);
        f[5] = f2bf((a1.y - mu) * rs * g1.y + b1.y);
        f[6] = f2bf((a1.z - mu) * rs * g1.z + b1.z);
        f[7] = f2bf((a1.w - mu) * rs * g1.w + b1.w);
        int byte = (((gw * 8 + kb) * 64 + lf0 + g * 16) << 4) ^ (((kb >> 1) & 3) << 5);
        *(bf16x8*)((char*)A_lds + byte) = f;
      }
    }
  }
  __syncthreads();

  // ---- MFMA: [16 rows/wave] x [64 cols K|V] x 256 ----
  {
    const int w = t >> 6, l = t & 63;
    const int lm = l & 15, g = l >> 4;
    f32x4 acc[4];
#pragma unroll
    for (int ni = 0; ni < 4; ++ni) acc[ni] = (f32x4){0.f, 0.f, 0.f, 0.f};
#pragma unroll
    for (int kb = 0; kb < 8; ++kb) {
      const int byte = (((w * 8 + kb) * 64 + l) << 4) ^ (((kb >> 1) & 3) << 5);
      const bf16x8 a = *(const bf16x8*)((char*)A_lds + byte);
      bf16x8 bfr[4];
#pragma unroll
      for (int ni = 0; ni < 4; ++ni)
        bfr[ni] = *(const bf16x8*)(wkvB + (((size_t)kb * 64 + lm + ni * 16) * 4 + g) * 8);
#pragma unroll
      for (int ni = 0; ni < 4; ++ni)
        acc[ni] = __builtin_amdgcn_mfma_f32_16x16x32_bf16(a, bfr[ni], acc[ni], 0, 0, 0);
    }
#pragma unroll
    for (int ni = 0; ni < 4; ++ni) {
      const int col = lm + ni * 16;
      float* Out = (col < 32) ? K_ws : V_ws;
      const int cc = col & 31;
#pragma unroll
      for (int reg = 0; reg < 4; ++reg) {
        const int s = s0 + w * 16 + g * 4 + reg;
        Out[((size_t)s * R_DIM + r) * 32 + cc] = acc[ni][reg];
      }
    }
  }

  // ---- pool: masked column sums from frag LDS (rotated rows) ----
  {
    const int lc = t & 63;   // cols lc*4..lc*4+3
    const int wq = t >> 6;   // row group wq*16..+15
    const int kb = lc >> 3, g2 = (lc >> 1) & 3, bh = (lc & 1) * 4;
    float4 ps = make_float4(0.f, 0.f, 0.f, 0.f);
    for (int i = 0; i < 16; ++i) {
      const int rloc = (i + lc) & 15;
      const int byte =
          ((((wq * 8 + kb) * 64 + rloc + g2 * 16) << 4) + bh * 2) ^ (((kb >> 1) & 3) << 5);
      const short4 xb = *(const short4*)((char*)A_lds + byte);
      const float mk = mask_s[wq * 16 + rloc];
      ps.x += mk * bf2f(xb.x);
      ps.y += mk * bf2f(xb.y);
      ps.z += mk * bf2f(xb.z);
      ps.w += mk * bf2f(xb.w);
    }
    poolp[wq][lc] = ps;
  }
  __syncthreads();
  if (t < 64) {
    const float4 a = poolp[0][t], b = poolp[1][t], c = poolp[2][t], d = poolp[3][t];
    atomicAdd(&pool_ws[r * C_DIM + t * 4 + 0], a.x + b.x + c.x + d.x);
    atomicAdd(&pool_ws[r * C_DIM + t * 4 + 1], a.y + b.y + c.y + d.y);
    atomicAdd(&pool_ws[r * C_DIM + t * 4 + 2], a.z + b.z + c.z + d.z);
    atomicAdd(&pool_ws[r * C_DIM + t * 4 + 3], a.w + b.w + c.w + d.w);
  }
}

// ---------------- K2: finalize pool, compute Q -----------------------------
__global__ __launch_bounds__(256, 2)
void k2_q(const float* __restrict__ pool_ws, const int* __restrict__ mask,
          const float* __restrict__ w_q, float* __restrict__ Q_ws) {
  __shared__ float qp[256];
  __shared__ float wsum[4];
  const int r = blockIdx.x, t = threadIdx.x;
  int cnt = 0;
  for (int s = t; s < S_DIM; s += 256) cnt += mask[s * R_DIM + r];
  float cf = wred((float)cnt);
  if ((t & 63) == 0) wsum[t >> 6] = cf;
  __syncthreads();
  const float denom = wsum[0] + wsum[1] + wsum[2] + wsum[3] + 1e-10f;
  qp[t] = pool_ws[r * C_DIM + t] / denom;
  __syncthreads();
  float acc = 0.f;
  for (int c = 0; c < 256; ++c) acc += qp[c] * w_q[c * 256 + t];
  Q_ws[r * 256 + t] = acc * SCALE;
}

// ---------------- K3: logits + softmax over s + O --------------------------
__global__ __launch_bounds__(256, 2)
void k3_attn(const float* __restrict__ K_ws, const float* __restrict__ V_ws,
             const int* __restrict__ mask, const float* __restrict__ Q_ws,
             float* __restrict__ O_ws) {
  __shared__ float q[256];
  __shared__ float lg[1024 * 9];
  __shared__ float kv[256 * 36];
  __shared__ float mh[8], inv[8];
  const int r = blockIdx.x, t = threadIdx.x;
  q[t] = Q_ws[r * 256 + t];

  for (int ch = 0; ch < 4; ++ch) {
    const int sb = ch * 256;
    __syncthreads();
    for (int f = t; f < 2048; f += 256) {
      const int sl = f >> 3, dq = f & 7;
      *(float4*)(kv + sl * 36 + dq * 4) =
          *(const float4*)(K_ws + ((size_t)(sb + sl) * R_DIM + r) * 32 + dq * 4);
    }
    __syncthreads();
    float kr[32];
#pragma unroll
    for (int dq = 0; dq < 8; ++dq)
      *(float4*)(kr + dq * 4) = *(float4*)(kv + t * 36 + dq * 4);
    const float bias = mask[(sb + t) * R_DIM + r] ? 0.f : -1e9f;
#pragma unroll
    for (int h = 0; h < 8; ++h) {
      float a = 0.f;
#pragma unroll
      for (int d = 0; d < 32; ++d) a += q[h * 32 + d] * kr[d];
      lg[(sb + t) * 9 + h] = a + bias;
    }
  }
  __syncthreads();
  {
    const int h = t >> 5, l32 = t & 31;
    float mx = -INFINITY;
    for (int k = 0; k < 32; ++k) mx = fmaxf(mx, lg[(l32 + 32 * k) * 9 + h]);
#pragma unroll
    for (int mk = 16; mk >= 1; mk >>= 1) mx = fmaxf(mx, __shfl_xor(mx, mk, 64));
    float sm = 0.f;
    for (int k = 0; k < 32; ++k) sm += expf(lg[(l32 + 32 * k) * 9 + h] - mx);
#pragma unroll
    for (int mk = 16; mk >= 1; mk >>= 1) sm += __shfl_xor(sm, mk, 64);
    if (l32 == 0) { mh[h] = mx; inv[h] = 1.f / sm; }
  }
  __syncthreads();
  for (int f = t; f < 8192; f += 256) {
    const int s = f >> 3, h = f & 7;
    lg[s * 9 + h] = expf(lg[s * 9 + h] - mh[h]) * inv[h];
  }
  const int h = t >> 5, d = t & 31;
  float o = 0.f;
  for (int ch = 0; ch < 4; ++ch) {
    const int sb = ch * 256;
    __syncthreads();
    for (int f = t; f < 2048; f += 256) {
      const int sl = f >> 3, dq = f & 7;
      *(float4*)(kv + sl * 36 + dq * 4) =
          *(const float4*)(V_ws + ((size_t)(sb + sl) * R_DIM + r) * 32 + dq * 4);
    }
    __syncthreads();
    for (int sl = 0; sl < 256; ++sl)
      o += lg[(sb + sl) * 9 + h] * kv[sl * 36 + d];
  }
  O_ws[r * 256 + t] = o;
}

// ---------------- K4: MFMA gate GEMM + sigmoid*O + output GEMM -------------
__global__ __launch_bounds__(256, 2)
void k4_mfma(const float* __restrict__ mIn, const float* __restrict__ ln_g,
             const float* __restrict__ ln_b, const float* __restrict__ mu_ws,
             const float* __restrict__ rs_ws, const short* __restrict__ wgB,
             const float* __restrict__ b_g, const float* __restrict__ O_ws,
             const short* __restrict__ woB, const float* __restrict__ b_o,
             float* __restrict__ out) {
  __shared__ __align__(16) short A_lds[2048 * 8];  // 32 KB
  const int t = threadIdx.x;
  const int p0 = blockIdx.x * 64;
  const int r0 = p0 & 255;
  const int l = t & 63;
  const int w = t >> 6;
  const int lm = l & 15;
  const int g = l >> 4;

  {
    const int row = w * 16 + lm;
    const size_t p = (size_t)(p0 + row);
    const float mu = mu_ws[p], rs = rs_ws[p];
    const float* mrow = mIn + p * 256 + g * 8;
    const float* gp = ln_g + g * 8;
    const float* bp = ln_b + g * 8;
#pragma unroll
    for (int kb = 0; kb < 8; ++kb) {
      const float4 m0 = *(const float4*)(mrow + kb * 32);
      const float4 m1 = *(const float4*)(mrow + kb * 32 + 4);
      const float4 g0 = *(const float4*)(gp + kb * 32);
      const float4 g1 = *(const float4*)(gp + kb * 32 + 4);
      const float4 b0 = *(const float4*)(bp + kb * 32);
      const float4 b1 = *(const float4*)(bp + kb * 32 + 4);
      bf16x8 xf;
      xf[0] = f2bf((m0.x - mu) * rs * g0.x + b0.x);
      xf[1] = f2bf((m0.y - mu) * rs * g0.y + b0.y);
      xf[2] = f2bf((m0.z - mu) * rs * g0.z + b0.z);
      xf[3] = f2bf((m0.w - mu) * rs * g0.w + b0.w);
      xf[4] = f2bf((m1.x - mu) * rs * g1.x + b1.x);
      xf[5] = f2bf((m1.y - mu) * rs * g1.y + b1.y);
      xf[6] = f2bf((m1.z - mu) * rs * g1.z + b1.z);
      xf[7] = f2bf((m1.w - mu) * rs * g1.w + b1.w);
      *(bf16x8*)(A_lds + ((w * 8 + kb) * 64 + l) * 8) = xf;
    }
  }
  __syncthreads();

  const int nB = w * 64;
  const int col = nB + lm;
  f32x4 acc[4][4];

#pragma unroll
  for (int ni = 0; ni < 4; ++ni) {
    const float bg = b_g[col + ni * 16];
#pragma unroll
    for (int mi = 0; mi < 4; ++mi) acc[mi][ni] = (f32x4){bg, bg, bg, bg};
  }
#pragma unroll
  for (int kb = 0; kb < 8; ++kb) {
    bf16x8 a[4], bb[4];
#pragma unroll
    for (int mi = 0; mi < 4; ++mi)
      a[mi] = *(const bf16x8*)(A_lds + ((mi * 8 + kb) * 64 + l) * 8);
#pragma unroll
    for (int ni = 0; ni < 4; ++ni)
      bb[ni] = *(const bf16x8*)(wgB + (((size_t)kb * 256 + col + ni * 16) * 4 + g) * 8);
#pragma unroll
    for (int mi = 0; mi < 4; ++mi)
#pragma unroll
      for (int ni = 0; ni < 4; ++ni)
        acc[mi][ni] = __builtin_amdgcn_mfma_f32_16x16x32_bf16(a[mi], bb[ni], acc[mi][ni], 0, 0, 0);
  }
  __syncthreads();

#pragma unroll
  for (int mi = 0; mi < 4; ++mi) {
#pragma unroll
    for (int ni = 0; ni < 4; ++ni) {
      const int c2 = col + ni * 16;
      const int kb2 = c2 >> 5, g2 = (c2 >> 3) & 3, b2 = c2 & 7;
#pragma unroll
      for (int reg = 0; reg < 4; ++reg) {
        const int row = mi * 16 + g * 4 + reg;
        const float o = O_ws[(r0 + row) * 256 + c2];
        const float gl = acc[mi][ni][reg];
        const float tv = o / (1.f + expf(-gl));
        A_lds[((mi * 8 + kb2) * 64 + (g * 4 + reg) + g2 * 16) * 8 + b2] = f2bf(tv);
      }
    }
  }
  __syncthreads();

#pragma unroll
  for (int ni = 0; ni < 4; ++ni) {
    const float bo = b_o[col + ni * 16];
#pragma unroll
    for (int mi = 0; mi < 4; ++mi) acc[mi][ni] = (f32x4){bo, bo, bo, bo};
  }
#pragma unroll
  for (int kb = 0; kb < 8; ++kb) {
    bf16x8 a[4], bb[4];
#pragma unroll
    for (int mi = 0; mi < 4; ++mi)
      a[mi] = *(const bf16x8*)(A_lds + ((mi * 8 + kb) * 64 + l) * 8);
#pragma unroll
    for (int ni = 0; ni < 4; ++ni)
      bb[ni] = *(const bf16x8*)(woB + (((size_t)kb * 256 + col + ni * 16) * 4 + g) * 8);
#pragma unroll
    for (int mi = 0; mi < 4; ++mi)
#pragma unroll
      for (int ni = 0; ni < 4; ++ni)
        acc[mi][ni] = __builtin_amdgcn_mfma_f32_16x16x32_bf16(a[mi], bb[ni], acc[mi][ni], 0, 0, 0);
  }

#pragma unroll
  for (int mi = 0; mi < 4; ++mi)
#pragma unroll
    for (int ni = 0; ni < 4; ++ni)
#pragma unroll
      for (int reg = 0; reg < 4; ++reg) {
        const int row = mi * 16 + g * 4 + reg;
        out[(size_t)(p0 + row) * 256 + col + ni * 16] = acc[mi][ni][reg];
      }
}

extern "C" void kernel_launch(void* const* d_in, const int* in_sizes, int n_in,
                              void* d_out, int out_size, void* d_ws, size_t ws_size,
                              hipStream_t stream) {
  const float* mIn  = (const float*)d_in[0];
  const float* ln_g = (const float*)d_in[1];
  const float* ln_b = (const float*)d_in[2];
  const float* w_q  = (const float*)d_in[3];
  const float* w_k  = (const float*)d_in[4];
  const float* w_v  = (const float*)d_in[5];
  const float* w_g  = (const float*)d_in[6];
  const float* b_g  = (const float*)d_in[7];
  const float* w_o  = (const float*)d_in[8];
  const float* b_o  = (const float*)d_in[9];
  const int*   mask = (const int*)d_in[10];
  float* outp = (float*)d_out;

  char* ws = (char*)d_ws;
  const size_t NP = (size_t)S_DIM * R_DIM;
  float* mu_ws   = (float*)ws;
  float* rs_ws   = mu_ws + NP;
  float* K_ws    = rs_ws + NP;
  float* V_ws    = K_ws + NP * 32;
  float* pool_ws = V_ws + NP * 32;
  float* Q_ws    = pool_ws + 65536;
  float* O_ws    = Q_ws + 65536;
  short* wgB     = (short*)(O_ws + 65536);
  short* woB     = wgB + 65536;
  short* wkvB    = woB + 65536;

  hipMemsetAsync(pool_ws, 0, 65536 * sizeof(float), stream);

  k0_prep<<<72, 256, 0, stream>>>(w_g, w_o, w_k, w_v, wgB, woB, wkvB);
  k1_ln_kv<<<dim3(S_DIM / 64, R_DIM), 256, 0, stream>>>(
      mIn, ln_g, ln_b, wkvB, mask, mu_ws, rs_ws, K_ws, V_ws, pool_ws);
  k2_q<<<R_DIM, 256, 0, stream>>>(pool_ws, mask, w_q, Q_ws);
  k3_attn<<<R_DIM, 256, 0, stream>>>(K_ws, V_ws, mask, Q_ws, O_ws);
  k4_mfma<<<S_DIM * R_DIM / 64, 256, 0, stream>>>(
      mIn, ln_g, ln_b, mu_ws, rs_ws, wgB, b_g, O_ws, woB, b_o, outp);
}